// Round 7
// baseline (392.875 us; speedup 1.0000x reference)
//
#include <hip/hip_runtime.h>
#include <hip/hip_bf16.h>

#define NPTS    524288
#define NG      64
#define GSZ     64
#define VOX     (GSZ*GSZ*GSZ)       // 262144
#define NODES   64
#define TILE    64                  // points per block
#define NBLK    (NPTS / TILE)       // 8192
#define K0      192                 // padded K for layer-0 (164 -> 192)
#define SF      200                 // Fsh row stride (bf16) - natural bank stagger
#define NCELL   4096                // 16^3 Morton cells
#define PREP_VB 16384               // vox-repack blocks in prep_fused
#define PREP_CB 2048                // sort-count blocks in prep_fused

typedef __attribute__((ext_vector_type(8))) short bf16x8;
typedef __attribute__((ext_vector_type(4))) float f32x4;

__device__ inline unsigned short f2bf(float f) {
    __hip_bfloat16 b = __float2bfloat16(f);
    union { __hip_bfloat16 h; unsigned short u; } cv; cv.h = b;
    return cv.u;
}
__device__ inline unsigned int pk2(float c0, float c1) {
    return (unsigned int)f2bf(c0) | ((unsigned int)f2bf(c1) << 16);
}
__device__ inline float bflo(unsigned int v) { return __uint_as_float(v << 16); }
__device__ inline float bfhi(unsigned int v) { return __uint_as_float(v & 0xffff0000u); }

__device__ inline int spread4(int v) {   // 4 bits -> bits 0,3,6,9
    return (v & 1) | ((v & 2) << 2) | ((v & 4) << 4) | ((v & 8) << 6);
}
__device__ inline int cell_of(float px, float py, float pz) {
    int cx = min(max((int)((px + 1.0f) * 8.0f), 0), 15);
    int cy = min(max((int)((py + 1.0f) * 8.0f), 0), 15);
    int cz = min(max((int)((pz + 1.0f) * 8.0f), 0), 15);
    return spread4(cx) | (spread4(cy) << 1) | (spread4(cz) << 2);
}

// Bricked vox layout: 2x2x2-voxel bricks (8 u32 = 32B), bricks linear in
// (bz,by,bx).  idx = (bz<<13 | by<<8 | bx<<3) + (lz<<2 | ly<<1 | lx).

// ---- fused prep: vox brick-repack + sort histogram + weight prep ----
// Weights FRAGMENT-CONTIGUOUS: w0f[((ks*4+nt)*64 + lane)*8 + j] holds
// W0[(ks*32 + (lane>>4)*8 + j)*64 + nt*16 + (lane&15)] (bf16, 0-pad k>=164).
__global__ void prep_fused(const float* __restrict__ fg, uint4* __restrict__ vox4,
                           const float* __restrict__ x, unsigned short* __restrict__ cid,
                           int* __restrict__ hist,
                           const float* __restrict__ W0, const float* __restrict__ W1,
                           unsigned short* __restrict__ w0f, unsigned short* __restrict__ w1f) {
    int b = blockIdx.x;
    int tid = threadIdx.x;
    if (b < PREP_VB) {
        int idx = b * 256 + tid;            // NG * VOX/4 total
        int g = idx >> 16;
        int hb = idx & 65535;
        int brick = hb >> 1;
        int h = hb & 1;                      // lz
        int bx = brick & 31, by = (brick >> 5) & 31, bz = brick >> 10;
        int xx = bx << 1, yy = by << 1, zz = (bz << 1) + h;
        const float* c0 = fg + (size_t)g * (2 * VOX) + ((zz << 6) + yy) * 64 + xx;
        const float* c1 = c0 + VOX;
        float2 a0 = *(const float2*)c0;
        float2 a1 = *(const float2*)(c0 + 64);
        float2 d0 = *(const float2*)c1;
        float2 d1 = *(const float2*)(c1 + 64);
        vox4[idx] = make_uint4(pk2(a0.x, d0.x), pk2(a0.y, d0.y),
                               pk2(a1.x, d1.x), pk2(a1.y, d1.y));
    } else if (b < PREP_VB + PREP_CB) {
        int p = (b - PREP_VB) * 256 + tid;
        int c = cell_of(x[p * 3 + 0], x[p * 3 + 1], x[p * 3 + 2]);
        cid[p] = (unsigned short)c;
        atomicAdd(&hist[c], 1);
    } else {
        int t = (b - PREP_VB - PREP_CB) * 256 + tid;   // 0..4095
        for (int i = t; i < 24 * 512; i += 4096) {     // w0f: 6ks*4nt*64*8 shorts
            int j = i & 7, ln = (i >> 3) & 63, fi = i >> 9;   // fi = ks*4+nt
            int ks = fi >> 2, nt = fi & 3;
            int k = ks * 32 + ((ln >> 4) << 3) + j, n = nt * 16 + (ln & 15);
            w0f[i] = (k < 164) ? f2bf(W0[k * NODES + n]) : (unsigned short)0;
        }
        {   // w1f: 2ks*4nt*64*8 = 4096 shorts, one per thread
            int i = t;
            int j = i & 7, ln = (i >> 3) & 63, fi = i >> 9;
            int ks = fi >> 2, nt = fi & 3;
            int k = ks * 32 + ((ln >> 4) << 3) + j, n = nt * 16 + (ln & 15);
            w1f[i] = f2bf(W1[k * NODES + n]);
        }
    }
}

// ---- sort 2: exclusive scan of 4096 bins ----
__global__ void sort_scan(const int* __restrict__ hist, int* __restrict__ offs) {
    __shared__ int partial[256];
    int t = threadIdx.x;
    int loc[16];
    int s = 0;
    #pragma unroll
    for (int i = 0; i < 16; ++i) { loc[i] = s; s += hist[t * 16 + i]; }
    partial[t] = s;
    __syncthreads();
    for (int d = 1; d < 256; d <<= 1) {
        int v = (t >= d) ? partial[t - d] : 0;
        __syncthreads();
        partial[t] += v;
        __syncthreads();
    }
    int base = partial[t] - s;      // exclusive
    #pragma unroll
    for (int i = 0; i < 16; ++i) offs[t * 16 + i] = base + loc[i];
}

// ---- sort 3: scatter points to sorted order ----
__global__ void sort_scatter(const float* __restrict__ x, const unsigned short* __restrict__ cell_id,
                             int* __restrict__ offs, float4* __restrict__ spts) {
    int p = blockIdx.x * blockDim.x + threadIdx.x;
    int c = cell_id[p];
    int pos = atomicAdd(&offs[c], 1);
    spts[pos] = make_float4(x[p * 3 + 0], x[p * 3 + 1], x[p * 3 + 2], __int_as_float(p));
}

// ---- pipelined gather: FLAT named state (no struct, no conditional init ->
// stays SSA/VGPR; R6's struct+branch version spilled to scratch: WRITE_SIZE 3x).

#define SDECL(S) \
    unsigned int S##c00, S##c01, S##c10, S##c11, S##c20, S##c21, S##c30, S##c31; \
    float S##zy00, S##zy01, S##zy10, S##zy11, S##xw0, S##xw1; \
    int S##col; bool S##wr;

// Unconditional issue: transform, validity, clamped-coord select (cndmask,
// keeps OOB/tail lanes' addresses safe without branches), gprep, 8 loads.
// Valid lanes' arithmetic identical to R2-R6 -> bit-identical output.
#define SISSUE(S, g_, part_, avail_) { \
    const int g = (g_); \
    float ix = (px * gscale[g*3+0] + gtrans[g*3+0] + 1.0f) * 31.5f; \
    float iy = (py * gscale[g*3+1] + gtrans[g*3+1] + 1.0f) * 31.5f; \
    float iz = (pz * gscale[g*3+2] + gtrans[g*3+2] + 1.0f) * 31.5f; \
    bool ok = !(part_) || ((ix >= -1.0f) & (ix < 64.0f) \
                         & (iy >= -1.0f) & (iy < 64.0f) \
                         & (iz >= -1.0f) & (iz < 64.0f)); \
    S##wr = (avail_) && ok; \
    float cx = S##wr ? ix : 0.0f; \
    float cy = S##wr ? iy : 0.0f; \
    float cz = S##wr ? iz : 0.0f; \
    float fx = floorf(cx), fy = floorf(cy), fz = floorf(cz); \
    int x0 = (int)fx, y0 = (int)fy, z0 = (int)fz; \
    float wx = cx - fx, wy = cy - fy, wz = cz - fz; \
    float wx0 = (x0 >= 0) ? (1.0f - wx) : 0.0f; \
    float wx1 = (x0 < 63) ? wx : 0.0f; \
    float wy0 = (y0 >= 0) ? (1.0f - wy) : 0.0f; \
    float wy1 = (y0 < 63) ? wy : 0.0f; \
    float wz0 = (z0 >= 0) ? (1.0f - wz) : 0.0f; \
    float wz1 = (z0 < 63) ? wz : 0.0f; \
    int xc0 = max(x0, 0), xc1 = min(x0 + 1, 63); \
    int yc0 = max(y0, 0), yc1 = min(y0 + 1, 63); \
    int zc0 = max(z0, 0), zc1 = min(z0 + 1, 63); \
    int xp0 = ((xc0 >> 1) << 3) | (xc0 & 1); \
    int xp1 = ((xc1 >> 1) << 3) | (xc1 & 1); \
    int yp0 = ((yc0 >> 1) << 8) | ((yc0 & 1) << 1); \
    int yp1 = ((yc1 >> 1) << 8) | ((yc1 & 1) << 1); \
    int zp0 = ((zc0 >> 1) << 13) | ((zc0 & 1) << 2); \
    int zp1 = ((zc1 >> 1) << 13) | ((zc1 & 1) << 2); \
    const unsigned int* vg = vox + ((size_t)g << 18); \
    S##c00 = vg[zp0 + yp0 + xp0]; S##c01 = vg[zp0 + yp0 + xp1]; \
    S##c10 = vg[zp0 + yp1 + xp0]; S##c11 = vg[zp0 + yp1 + xp1]; \
    S##c20 = vg[zp1 + yp0 + xp0]; S##c21 = vg[zp1 + yp0 + xp1]; \
    S##c30 = vg[zp1 + yp1 + xp0]; S##c31 = vg[zp1 + yp1 + xp1]; \
    S##zy00 = wz0 * wy0; S##zy01 = wz0 * wy1; \
    S##zy10 = wz1 * wy0; S##zy11 = wz1 * wy1; \
    S##xw0 = wx0; S##xw1 = wx1; \
    S##col = ptSF + 36 + 2 * g; \
}

// tree: accumulation order identical to R2-R6 original
#define STREE(S) if (S##wr) { \
    float f0 = 0.f, f1 = 0.f; \
    f0 += S##zy00 * (S##xw0 * bflo(S##c00) + S##xw1 * bflo(S##c01)); \
    f1 += S##zy00 * (S##xw0 * bfhi(S##c00) + S##xw1 * bfhi(S##c01)); \
    f0 += S##zy01 * (S##xw0 * bflo(S##c10) + S##xw1 * bflo(S##c11)); \
    f1 += S##zy01 * (S##xw0 * bfhi(S##c10) + S##xw1 * bfhi(S##c11)); \
    f0 += S##zy10 * (S##xw0 * bflo(S##c20) + S##xw1 * bflo(S##c21)); \
    f1 += S##zy10 * (S##xw0 * bfhi(S##c20) + S##xw1 * bfhi(S##c21)); \
    f0 += S##zy11 * (S##xw0 * bflo(S##c30) + S##xw1 * bflo(S##c31)); \
    f1 += S##zy11 * (S##xw0 * bfhi(S##c30) + S##xw1 * bfhi(S##c31)); \
    *(unsigned int*)&Fsh[S##col] = pk2(f0, f1); \
}

#define EXTRACT(gv, pv) \
    if (mf) { gv = (int)__builtin_ctzll(mf); mf &= mf - 1; pv = false; } \
    else if (mp) { gv = (int)__builtin_ctzll(mp); mp &= mp - 1; pv = true; } \
    else { gv = 0; pv = true; }

#define EXTRACT8 \
    int g0,g1,g2,g3,g4,g5,g6,g7; bool q0,q1,q2,q3,q4,q5,q6,q7; \
    EXTRACT(g0,q0) EXTRACT(g1,q1) EXTRACT(g2,q2) EXTRACT(g3,q3) \
    EXTRACT(g4,q4) EXTRACT(g5,q5) EXTRACT(g6,q6) EXTRACT(g7,q7) \
    int gA = sub==0?g0: sub==1?g1: sub==2?g2:g3; \
    bool qA = sub==0?q0: sub==1?q1: sub==2?q2:q3; \
    int gB = sub==0?g4: sub==1?g5: sub==2?g6:g7; \
    bool qB = sub==0?q4: sub==1?q5: sub==2?q6:q7;

// ---- main fused kernel: BARRIER-FREE (R5) + register-resident 2-deep
// pipelined gather with round-0 loads hidden under zero+PE (R7).
__global__ void __launch_bounds__(256, 4)
amrsrn_main(const float4* __restrict__ spts,
            const float* __restrict__ gscale,
            const float* __restrict__ gtrans,
            const unsigned int* __restrict__ vox,
            const unsigned short* __restrict__ w0f,
            const unsigned short* __restrict__ w1f,
            const float* __restrict__ b0,
            const float* __restrict__ b1,
            const float* __restrict__ W2,
            const float* __restrict__ b2,
            float* __restrict__ out) {
    __shared__ unsigned short Fsh[TILE * SF];   // 25600 B (only LDS)

    const int tid = threadIdx.x;
    const int lane = tid & 63;
    const int wv = tid >> 6;
    // coarse XCD swizzle: contiguous Morton octant per XCD -> L2 reuse
    const int cb = ((blockIdx.x & 7) << 10) | (blockIdx.x >> 3);
    const int base = cb * TILE;
    const int ptb = wv * 16;
    const int ptloc = lane >> 2;                // 16 points per wave
    const int sub = lane & 3;                   // 4 gather slots per point
    const int pt = ptb + ptloc;

    // ---- own point ----
    float4 sp = spts[base + pt];
    const float px = sp.x, py = sp.y, pz = sp.z;
    const int sreg = __float_as_int(sp.w);

    // ---- wave AABB + grid classification (registers only) ----
    float lox = px, hix = px, loy = py, hiy = py, loz = pz, hiz = pz;
    #pragma unroll
    for (int m = 1; m < 64; m <<= 1) {
        lox = fminf(lox, __shfl_xor(lox, m)); hix = fmaxf(hix, __shfl_xor(hix, m));
        loy = fminf(loy, __shfl_xor(loy, m)); hiy = fmaxf(hiy, __shfl_xor(hiy, m));
        loz = fminf(loz, __shfl_xor(loz, m)); hiz = fmaxf(hiz, __shfl_xor(hiz, m));
    }
    unsigned long long mf, mp;
    {
        int g = lane;
        float s0 = gscale[g*3+0], s1 = gscale[g*3+1], s2 = gscale[g*3+2];
        float t0 = gtrans[g*3+0], t1 = gtrans[g*3+1], t2 = gtrans[g*3+2];
        float xl = (lox*s0 + t0 + 1.0f)*31.5f, xh = (hix*s0 + t0 + 1.0f)*31.5f;
        float yl = (loy*s1 + t1 + 1.0f)*31.5f, yh = (hiy*s1 + t1 + 1.0f)*31.5f;
        float zl = (loz*s2 + t2 + 1.0f)*31.5f, zh = (hiz*s2 + t2 + 1.0f)*31.5f;
        bool fullg = (xl >= -0.999f) & (xh <= 63.999f)
                   & (yl >= -0.999f) & (yh <= 63.999f)
                   & (zl >= -0.999f) & (zh <= 63.999f);
        bool outg  = (xh < -1.001f) | (xl >= 64.001f)
                   | (yh < -1.001f) | (yl >= 64.001f)
                   | (zh < -1.001f) | (zl >= 64.001f);
        mf = __ballot(fullg);
        mp = __ballot(!fullg && !outg);
    }

    const int total = __popcll(mf) + __popcll(mp);
    const int ptSF = pt * SF;
    int done = 0;
    SDECL(A) SDECL(B) SDECL(C) SDECL(D)
    Awr = Bwr = Cwr = Dwr = false;

    // ---- issue round 0 NOW; its ~400cy latency hides under zero+PE below ----
    if (total > 0) {
        EXTRACT8;
        bool avA = (done + sub) < total, avB = (done + 4 + sub) < total;
        SISSUE(A, gA, qA, avA)
        SISSUE(B, gB, qB, avB)
        done += 8;
    }

    // ---- zero own 16 Fsh rows (LDS pipe, overlaps loads) ----
    {
        uint4* zp = (uint4*)(Fsh + ptb * SF);
        for (int i = lane; i < 16 * SF / 8; i += 64) zp[i] = make_uint4(0, 0, 0, 0);
    }

    // ---- PE: 16 pts x 36 taus = 64 lanes x 9 (trans pipe, overlaps loads) ----
    #pragma unroll
    for (int t = 0; t < 9; ++t) {
        int tau = sub * 9 + t;
        int tt = (tau < 18) ? tau : tau - 18;
        int l = tt / 3, d = tt - l * 3;
        float c = (d == 0) ? px : ((d == 1) ? py : pz);
        float ang = c * (3.14159265358979323846f * (float)(1 << l));
        float val = (tau < 18) ? __sinf(ang) : __cosf(ang);
        Fsh[pt * SF + tau] = f2bf(val);
    }

    // ---- steady 2-deep pipeline: issue r+1 before treeing r ----
    if (total > 0) {
        while (done < total) {
            {
                EXTRACT8;
                bool avA = (done + sub) < total, avB = (done + 4 + sub) < total;
                SISSUE(C, gA, qA, avA)
                SISSUE(D, gB, qB, avB)
                done += 8;
            }
            STREE(A) STREE(B)
            if (done >= total) { STREE(C) STREE(D) goto gdone; }
            {
                EXTRACT8;
                bool avA = (done + sub) < total, avB = (done + 4 + sub) < total;
                SISSUE(A, gA, qA, avA)
                SISSUE(B, gB, qB, avB)
                done += 8;
            }
            STREE(C) STREE(D)
        }
        STREE(A) STREE(B)
gdone:  ;
    }

    // ---- MFMA MLP on own 16 rows (same-wave, no barrier) ----
    const int row = lane & 15;
    const int quad = lane >> 4;

    f32x4 acc0[4] = {{0,0,0,0},{0,0,0,0},{0,0,0,0},{0,0,0,0}};
    #pragma unroll
    for (int ks = 0; ks < 6; ++ks) {
        bf16x8 a = *(const bf16x8*)&Fsh[(ptb + row) * SF + ks * 32 + quad * 8];
        #pragma unroll
        for (int nt = 0; nt < 4; ++nt) {
            bf16x8 b = *(const bf16x8*)&w0f[(((ks << 2) + nt) << 9) + (lane << 3)];
            acc0[nt] = __builtin_amdgcn_mfma_f32_16x16x32_bf16(a, b, acc0[nt], 0, 0, 0);
        }
    }
    #pragma unroll
    for (int nt = 0; nt < 4; ++nt) {
        int node = nt * 16 + row;
        float bb = b0[node];
        #pragma unroll
        for (int r = 0; r < 4; ++r) {
            float h = acc0[nt][r] + bb;
            float s = __sinf(h);
            h = 0.5f * h + s * s;
            Fsh[(ptb + quad * 4 + r) * SF + node] = f2bf(h);
        }
    }

    f32x4 acc1[4] = {{0,0,0,0},{0,0,0,0},{0,0,0,0},{0,0,0,0}};
    #pragma unroll
    for (int ks = 0; ks < 2; ++ks) {
        bf16x8 a = *(const bf16x8*)&Fsh[(ptb + row) * SF + ks * 32 + quad * 8];
        #pragma unroll
        for (int nt = 0; nt < 4; ++nt) {
            bf16x8 b = *(const bf16x8*)&w1f[(((ks << 2) + nt) << 9) + (lane << 3)];
            acc1[nt] = __builtin_amdgcn_mfma_f32_16x16x32_bf16(a, b, acc1[nt], 0, 0, 0);
        }
    }
    float part[4] = {0.f, 0.f, 0.f, 0.f};
    #pragma unroll
    for (int nt = 0; nt < 4; ++nt) {
        int node = nt * 16 + row;
        float b1v = b1[node];
        float w2v = W2[node];
        #pragma unroll
        for (int r = 0; r < 4; ++r) {
            float h = acc1[nt][r] + b1v;
            float s = __sinf(h);
            h = 0.5f * h + s * s;
            part[r] += h * w2v;
        }
    }
    #pragma unroll
    for (int m = 1; m < 16; m <<= 1) {
        #pragma unroll
        for (int r = 0; r < 4; ++r) part[r] += __shfl_xor(part[r], m);
    }
    int o0 = __shfl(sreg, (quad * 4 + 0) << 2);
    int o1 = __shfl(sreg, (quad * 4 + 1) << 2);
    int o2 = __shfl(sreg, (quad * 4 + 2) << 2);
    int o3 = __shfl(sreg, (quad * 4 + 3) << 2);
    if (row == 0) {
        float b2v = b2[0];
        out[o0] = part[0] + b2v;
        out[o1] = part[1] + b2v;
        out[o2] = part[2] + b2v;
        out[o3] = part[3] + b2v;
    }
}

// ---- fallback (no workspace): direct fp32 kernel ----
__global__ void amrsrn_fallback(const float* __restrict__ x,
                                const float* __restrict__ gscale,
                                const float* __restrict__ gtrans,
                                const float* __restrict__ fg,
                                const float* __restrict__ W0,
                                const float* __restrict__ b0,
                                const float* __restrict__ W1,
                                const float* __restrict__ b1,
                                const float* __restrict__ W2,
                                const float* __restrict__ b2,
                                float* __restrict__ out) {
    int p = blockIdx.x * blockDim.x + threadIdx.x;
    float px = x[p*3+0], py = x[p*3+1], pz = x[p*3+2];
    float h0[NODES];
    #pragma unroll
    for (int j = 0; j < NODES; ++j) h0[j] = b0[j];
    #pragma unroll
    for (int l = 0; l < 6; ++l) {
        float freq = 3.14159265358979323846f * (float)(1 << l);
        #pragma unroll
        for (int d = 0; d < 3; ++d) {
            float v = (d == 0 ? px : (d == 1 ? py : pz)) * freq;
            float s = __sinf(v), c = __cosf(v);
            const float* wrs = W0 + (l*3 + d) * NODES;
            const float* wrc = W0 + (18 + l*3 + d) * NODES;
            #pragma unroll
            for (int j = 0; j < NODES; ++j) h0[j] += s * wrs[j] + c * wrc[j];
        }
    }
    for (int g = 0; g < NG; ++g) {
        float ix = (px * gscale[g*3+0] + gtrans[g*3+0] + 1.0f) * 31.5f;
        float iy = (py * gscale[g*3+1] + gtrans[g*3+1] + 1.0f) * 31.5f;
        float iz = (pz * gscale[g*3+2] + gtrans[g*3+2] + 1.0f) * 31.5f;
        float fxf = floorf(ix), fyf = floorf(iy), fzf = floorf(iz);
        int x0 = (int)fxf, y0 = (int)fyf, z0 = (int)fzf;
        float wx = ix - fxf, wy = iy - fyf, wz = iz - fzf;
        bool any = (x0 >= -1 && x0 < GSZ) && (y0 >= -1 && y0 < GSZ) && (z0 >= -1 && z0 < GSZ);
        if (any) {
            float f0 = 0.f, f1 = 0.f;
            #pragma unroll
            for (int dz = 0; dz < 2; ++dz) {
                int zi = z0 + dz; bool vz = ((unsigned)zi < (unsigned)GSZ);
                int zc = min(max(zi, 0), GSZ - 1);
                float wzf = dz ? wz : 1.f - wz;
                #pragma unroll
                for (int dy = 0; dy < 2; ++dy) {
                    int yi = y0 + dy; bool vy = ((unsigned)yi < (unsigned)GSZ);
                    int yc = min(max(yi, 0), GSZ - 1);
                    float wyf = dy ? wy : 1.f - wy;
                    int rowoff = (zc * GSZ + yc) * GSZ;
                    #pragma unroll
                    for (int dx = 0; dx < 2; ++dx) {
                        int xi = x0 + dx; bool vx = ((unsigned)xi < (unsigned)GSZ);
                        int xc = min(max(xi, 0), GSZ - 1);
                        float w = wzf * wyf * (dx ? wx : 1.f - wx);
                        w = (vz && vy && vx) ? w : 0.f;
                        const float* gp = fg + ((size_t)g << 19);
                        f0 += w * gp[rowoff + xc];
                        f1 += w * gp[VOX + rowoff + xc];
                    }
                }
            }
            const float* wr = W0 + (36 + 2*g) * NODES;
            #pragma unroll
            for (int j = 0; j < NODES; ++j) h0[j] += f0 * wr[j] + f1 * wr[NODES + j];
        }
    }
    #pragma unroll
    for (int j = 0; j < NODES; ++j) { float s = __sinf(h0[j]); h0[j] = 0.5f * h0[j] + s * s; }
    float out_acc = b2[0];
    #pragma unroll
    for (int half = 0; half < 2; ++half) {
        float h1[32];
        #pragma unroll
        for (int j = 0; j < 32; ++j) h1[j] = b1[half*32 + j];
        #pragma unroll
        for (int i = 0; i < NODES; ++i) {
            float a = h0[i];
            const float* w1r = W1 + i * NODES + half*32;
            #pragma unroll
            for (int j = 0; j < 32; ++j) h1[j] += a * w1r[j];
        }
        #pragma unroll
        for (int j = 0; j < 32; ++j) { float s = __sinf(h1[j]); out_acc += (0.5f * h1[j] + s * s) * W2[half*32 + j]; }
    }
    out[p] = out_acc;
}

extern "C" void kernel_launch(void* const* d_in, const int* in_sizes, int n_in,
                              void* d_out, int out_size, void* d_ws, size_t ws_size,
                              hipStream_t stream) {
    const float* x      = (const float*)d_in[0];
    const float* gscale = (const float*)d_in[1];
    const float* gtrans = (const float*)d_in[2];
    const float* fg     = (const float*)d_in[3];
    const float* W0     = (const float*)d_in[4];
    const float* b0     = (const float*)d_in[5];
    const float* W1     = (const float*)d_in[6];
    const float* b1     = (const float*)d_in[7];
    const float* W2     = (const float*)d_in[8];
    const float* b2     = (const float*)d_in[9];
    float* out = (float*)d_out;

    char* wsp = (char*)d_ws;
    unsigned short* w0f = (unsigned short*)wsp;            // 24576 B
    unsigned short* w1f = w0f + 24 * 512;                  // 8192 B
    int* hist           = (int*)(wsp + (64 << 10));
    int* offs           = (int*)(wsp + (80 << 10));
    unsigned short* cid = (unsigned short*)(wsp + (96 << 10));
    float4* spts        = (float4*)(wsp + (96 << 10) + (1 << 20));
    unsigned int* vox   = (unsigned int*)(wsp + (96 << 10) + (1 << 20) + (8 << 20));
    const size_t ws_needed = (96 << 10) + (1 << 20) + (8 << 20) + (size_t)NG * VOX * 4;

    if (ws_size >= ws_needed) {
        hipMemsetAsync(hist, 0, NCELL * sizeof(int), stream);
        prep_fused<<<PREP_VB + PREP_CB + 16, 256, 0, stream>>>(
            fg, (uint4*)vox, x, cid, hist, W0, W1, w0f, w1f);
        sort_scan<<<1, 256, 0, stream>>>(hist, offs);
        sort_scatter<<<NPTS / 256, 256, 0, stream>>>(x, cid, offs, spts);
        amrsrn_main<<<NBLK, 256, 0, stream>>>(spts, gscale, gtrans, vox,
                                              w0f, w1f, b0, b1, W2, b2, out);
    } else {
        amrsrn_fallback<<<NPTS / 256, 256, 0, stream>>>(
            x, gscale, gtrans, fg, W0, b0, W1, b1, W2, b2, out);
    }
}